// Round 7
// baseline (33.756 us; speedup 1.0000x reference)
//
#include <hip/hip_runtime.h>

// QuantumAttention: out[b,s,e] = sum_q q[b,s,q] * W_dec[e,q] + x[b,s,e]
//   angles = x @ W_enc^T, c = cos(angles)
//   q[0] = prod(c[1..7]); q[i] = prod(c[0..i])
//
// R7: single-shot blocks, one front-loaded VMEM burst (4 x-loads then 16
// weight loads = 20 KB/wave in flight), then pure compute. No loop => the
// allocator can't sink weight loads back into a loop (R6: VGPR=60 proved
// it re-loaded weights from L2 every iteration, correlated 4-wave stalls).
// launch_bounds(256,2) -> <=128 VGPR, 16 waves/CU; block churn pipelines
// load bursts under compute across blocks.

typedef float v2f __attribute__((ext_vector_type(2)));
typedef float v4f __attribute__((ext_vector_type(4)));

#define EDIM 1024
#define QDIM 8
#define NTOK 16384
#define BLOCK 256
#define T 4
#define GRID (NTOK / T)   // 4096

// v += dpp_move(v); bound_ctrl=true -> out-of-range lanes contribute 0
template<int CTRL>
__device__ __forceinline__ float dpp_add(float v) {
    int m = __builtin_amdgcn_update_dpp(0, __float_as_int(v), CTRL, 0xF, 0xF, true);
    return v + __int_as_float(m);
}

// 64-lane sum on the VALU pipe; result valid in lane 63 only.
__device__ __forceinline__ float wave_sum63(float v) {
    v = dpp_add<0x111>(v);   // row_shr:1
    v = dpp_add<0x112>(v);   // row_shr:2
    v = dpp_add<0x114>(v);   // row_shr:4
    v = dpp_add<0x118>(v);   // row_shr:8
    v = dpp_add<0x142>(v);   // row_bcast:15
    v = dpp_add<0x143>(v);   // row_bcast:31
    return v;
}

__global__ __launch_bounds__(BLOCK, 2)
void qattn_kernel(const float* __restrict__ x,
                  const float* __restrict__ W_enc,   // [Q][E]
                  const float* __restrict__ W_dec,   // [E][Q]
                  float* __restrict__ out)
{
    __shared__ float red[T][4][QDIM];

    const int t    = threadIdx.x;
    const int lane = t & 63;
    const int wave = t >> 6;
    const int e0   = t * 4;

    const int tok0 = blockIdx.x * T;

    // ---- one load burst: x first (HBM, longest latency), then weights (L2) ----
    v4f xv[T];
#pragma unroll
    for (int i = 0; i < T; ++i)
        xv[i] = *(const v4f*)(x + (size_t)(tok0 + i) * EDIM + e0);

    v4f we[QDIM / 2][2];   // wenc as pairs-of-rows packed in v4f: [q/2][half]
#pragma unroll
    for (int q = 0; q < QDIM; ++q)
        *((v2f*)&we[q >> 1][0] + 0) = (v2f){0.f, 0.f};  // placate init (overwritten)
    v4f wenc[QDIM];
#pragma unroll
    for (int q = 0; q < QDIM; ++q)
        wenc[q] = *(const v4f*)(W_enc + q * EDIM + e0);

    v4f wdlo[4], wdhi[4];  // W_dec[e0+j][0..3], [4..7]
#pragma unroll
    for (int j = 0; j < 4; ++j) {
        wdlo[j] = *(const v4f*)(W_dec + (e0 + j) * QDIM);
        wdhi[j] = *(const v4f*)(W_dec + (e0 + j) * QDIM + 4);
    }

    // ---- encode: packed dot4 per (token, q) ----
    float ang[T][QDIM];
#pragma unroll
    for (int i = 0; i < T; ++i) {
        v2f x01 = (v2f){xv[i].x, xv[i].y};
        v2f x23 = (v2f){xv[i].z, xv[i].w};
#pragma unroll
        for (int q = 0; q < QDIM; ++q) {
            v2f w01 = (v2f){wenc[q].x, wenc[q].y};
            v2f w23 = (v2f){wenc[q].z, wenc[q].w};
            v2f acc = x01 * w01;
            acc = __builtin_elementwise_fma(x23, w23, acc);
            ang[i][q] = acc.x + acc.y;
        }
    }

    // ---- 64-lane DPP reduce (VALU pipe), sums land in lane 63 ----
#pragma unroll
    for (int i = 0; i < T; ++i)
#pragma unroll
        for (int q = 0; q < QDIM; ++q)
            ang[i][q] = wave_sum63(ang[i][q]);

    // ---- cross-wave combine: lane 63 publishes, one barrier ----
    if (lane == 63) {
#pragma unroll
        for (int i = 0; i < T; ++i) {
            *(v4f*)&red[i][wave][0] = (v4f){ang[i][0], ang[i][1], ang[i][2], ang[i][3]};
            *(v4f*)&red[i][wave][4] = (v4f){ang[i][4], ang[i][5], ang[i][6], ang[i][7]};
        }
    }
    __syncthreads();

#pragma unroll
    for (int i = 0; i < T; ++i) {
        // sum 4 wave partials (broadcast v4f reads, conflict-free)
        v4f slo = (v4f){0.f, 0.f, 0.f, 0.f};
        v4f shi = (v4f){0.f, 0.f, 0.f, 0.f};
#pragma unroll
        for (int w = 0; w < 4; ++w) {
            slo += *(const v4f*)&red[i][w][0];
            shi += *(const v4f*)&red[i][w][4];
        }
        float c[QDIM];
        c[0] = __cosf(slo.x); c[1] = __cosf(slo.y);
        c[2] = __cosf(slo.z); c[3] = __cosf(slo.w);
        c[4] = __cosf(shi.x); c[5] = __cosf(shi.y);
        c[6] = __cosf(shi.z); c[7] = __cosf(shi.w);

        // q-values: q[0] = c1*...*c7 ; q[i] = c0*...*ci
        float qv[QDIM];
        float q0 = c[1];
#pragma unroll
        for (int q = 2; q < QDIM; ++q) q0 *= c[q];
        qv[0] = q0;
        float p = c[0];
#pragma unroll
        for (int q = 1; q < QDIM; ++q) { p *= c[q]; qv[q] = p; }

        v4f qlo = (v4f){qv[0], qv[1], qv[2], qv[3]};
        v4f qhi = (v4f){qv[4], qv[5], qv[6], qv[7]};

        // ---- decode (packed v4f: 2 fma4 per output elem) + residual ----
        float oacc[4];
#pragma unroll
        for (int j = 0; j < 4; ++j) {
            v4f a = qlo * wdlo[j];
            a = __builtin_elementwise_fma(qhi, wdhi[j], a);
            v2f h = (v2f){a.x, a.y} + (v2f){a.z, a.w};
            oacc[j] = h.x + h.y;
        }
        v4f o = xv[i] + (v4f){oacc[0], oacc[1], oacc[2], oacc[3]};
        __builtin_nontemporal_store(o, (v4f*)(out + (size_t)(tok0 + i) * EDIM + e0));
    }
}

extern "C" void kernel_launch(void* const* d_in, const int* in_sizes, int n_in,
                              void* d_out, int out_size, void* d_ws, size_t ws_size,
                              hipStream_t stream) {
    const float* x     = (const float*)d_in[0];
    const float* W_enc = (const float*)d_in[1];
    const float* W_dec = (const float*)d_in[2];
    float* out         = (float*)d_out;

    hipLaunchKernelGGL(qattn_kernel, dim3(GRID), dim3(BLOCK), 0, stream,
                       x, W_enc, W_dec, out);
}